// Round 9
// baseline (2560.286 us; speedup 1.0000x reference)
//
#include <hip/hip_runtime.h>

constexpr int PDIM = 127;   // previous_embed_size
constexpr int ADIM = 128;   // agg features
constexpr int ODIM = 255;   // w2 out size
constexpr int RTILE = 32;
constexpr int CAP = 80;     // bucket capacity per node (deg ~ Pois(20))
constexpr float EPS = 1e-5f;

constexpr int XS_STRIDE = 136;  // bf16 elems; 272B row stride (16B-aligned rows)
constexpr int CS_STRIDE = 264;  // 528B row stride

typedef short bf16x8 __attribute__((ext_vector_type(8)));
typedef float f32x4 __attribute__((ext_vector_type(4)));

__device__ inline unsigned short f2b(float x) {  // f32 -> bf16 RNE
    unsigned u = __builtin_bit_cast(unsigned, x);
    u += 0x7FFF + ((u >> 16) & 1);
    return (unsigned short)(u >> 16);
}

// ---------------- build: buckets + (tail blocks) weight conversion
// code = e | (side << 20); side 0 -> contribution is ru[e], side 1 -> rv[e]
__global__ __launch_bounds__(256) void build_kernel(
    const int* __restrict__ u, const int* __restrict__ v,
    int* __restrict__ cnt, int* __restrict__ bucket, int E, int nbB,
    const float* __restrict__ w1, const float* __restrict__ w2,
    unsigned short* __restrict__ w1b, unsigned short* __restrict__ w2b)
{
    int b = blockIdx.x;
    if (b < nbB) {
        int e = b * 256 + threadIdx.x;
        if (e >= E) return;
        int vn = v[e];
        int slot = atomicAdd(&cnt[vn], 1);
        if (slot < CAP) bucket[(long long)vn * CAP + slot] = e;            // side 0
        int un = u[e];
        slot = atomicAdd(&cnt[un], 1);
        if (slot < CAP) bucket[(long long)un * CAP + slot] = e | (1 << 20); // side 1
    } else {
        int t = (b - nbB) * 256 + threadIdx.x;
        if (t < 65536) {
            int o = t >> 8, k = t & 255;
            w2b[t] = (o < ODIM && k < ODIM) ? f2b(w2[o * ODIM + k]) : (unsigned short)0;
        } else {
            int s = t - 65536;   // 128*128 = 16384
            if (s < ADIM * ADIM) w1b[s] = f2b(w1[s]);
        }
    }
}

// ---------------- gather + wave-local column stats (NO block barrier)
// one HALF-WAVE per node; lane l owns cols 4l..4l+3 (lane 31: quad at 123 ->
// cols 124..126 via .y.z.w; col 127 = sum g[e], accumulated by lane 31 only).
// Stats: lanes l and l^32 own the same cols for the wave's two nodes; one
// shfl_xor(32) combines them, then lanes<32 write csum, lanes>=32 csumsq.
__global__ __launch_bounds__(256) void gather_kernel(
    const int* __restrict__ cnt, const int* __restrict__ bucket,
    const float* __restrict__ g,
    const float* __restrict__ ru, const float* __restrict__ rv,
    float* __restrict__ agg, float* __restrict__ csum,
    float* __restrict__ csumsq, int N)
{
    __shared__ int codes[8][CAP];   // 8 half-waves per 256-thread block
    int tid = threadIdx.x;
    int hw = tid >> 5;              // half-wave id in block
    int sub = tid & 31;             // lane within half-wave
    long long node = (long long)blockIdx.x * 8 + hw;
    bool valid = (node < N);
    int nd = valid ? (int)node : 0;
    int deg = valid ? cnt[nd] : 0;  // invalid -> deg 0 -> zero partials
    if (deg > CAP) deg = CAP;
    const int* bkt = bucket + (long long)nd * CAP;
    // stage codes (coalesced; same-wave DS ordering, no barrier needed)
    codes[hw][sub] = bkt[sub];
    codes[hw][32 + sub] = bkt[32 + sub];
    if (sub < CAP - 64) codes[hw][64 + sub] = bkt[64 + sub];

    int eoff = (sub < 31) ? 4 * sub : 123;   // element offset of this lane's quad
    f32x4 acc = {0.f, 0.f, 0.f, 0.f};
    float gacc = 0.f;
    bool g31 = (sub == 31);
    int d = 0;
    for (; d + 4 <= deg; d += 4) {
        f32x4 vb[4];
        float gb[4];
        #pragma unroll
        for (int k = 0; k < 4; ++k) {
            int c = codes[hw][d + k];
            int e = c & 0xFFFFF;
            const float* s = (c & (1 << 20)) ? rv : ru;
            vb[k] = *reinterpret_cast<const f32x4*>(s + (long long)e * PDIM + eoff);
            gb[k] = g31 ? g[e] : 0.f;
        }
        #pragma unroll
        for (int k = 0; k < 4; ++k) { acc += vb[k]; gacc += gb[k]; }
    }
    for (; d < deg; ++d) {
        int c = codes[hw][d];
        int e = c & 0xFFFFF;
        const float* s = (c & (1 << 20)) ? rv : ru;
        acc += *reinterpret_cast<const f32x4*>(s + (long long)e * PDIM + eoff);
        if (g31) gacc += g[e];
    }

    // agg row write (guarded; do NOT return early — stats need all lanes)
    if (valid) {
        float* arow = agg + node * ADIM;
        if (sub < 31) {
            *reinterpret_cast<f32x4*>(arow + 4 * sub) = acc;
        } else {
            f32x4 o; o.x = acc.y; o.y = acc.z; o.z = acc.w; o.w = gacc;
            *reinterpret_cast<f32x4*>(arow + 124) = o;
        }
    }

    // per-node col partials (lane31: cols 124..127 from .y.z.w + gacc;
    // its .x duplicates col 123 owned by lane 30 -> excluded)
    int cbase = (sub < 31) ? 4 * sub : 124;
    float v0 = (sub < 31) ? acc.x : acc.y;
    float v1 = (sub < 31) ? acc.y : acc.z;
    float v2 = (sub < 31) ? acc.z : acc.w;
    float v3 = (sub < 31) ? acc.w : gacc;
    // combine the wave's two nodes (partner lane owns the same cols)
    float p0 = __shfl_xor(v0, 32, 64);
    float p1 = __shfl_xor(v1, 32, 64);
    float p2 = __shfl_xor(v2, 32, 64);
    float p3 = __shfl_xor(v3, 32, 64);
    if ((tid & 63) < 32) {
        unsafeAtomicAdd(&csum[cbase + 0], v0 + p0);
        unsafeAtomicAdd(&csum[cbase + 1], v1 + p1);
        unsafeAtomicAdd(&csum[cbase + 2], v2 + p2);
        unsafeAtomicAdd(&csum[cbase + 3], v3 + p3);
    } else {
        unsafeAtomicAdd(&csumsq[cbase + 0], v0 * v0 + p0 * p0);
        unsafeAtomicAdd(&csumsq[cbase + 1], v1 * v1 + p1 * p1);
        unsafeAtomicAdd(&csumsq[cbase + 2], v2 * v2 + p2 * p2);
        unsafeAtomicAdd(&csumsq[cbase + 3], v3 * v3 + p3 * p3);
    }
}

// ---------------- mean/var -> BN scale/shift
__global__ void finalize_kernel(const float* __restrict__ csum,
                                const float* __restrict__ csumsq,
                                const float* __restrict__ gamma,
                                const float* __restrict__ beta,
                                float* __restrict__ scale,
                                float* __restrict__ shift, int N)
{
    int j = threadIdx.x;
    if (j >= ADIM) return;
    float inv = 1.f / (float)N;
    float mean = csum[j] * inv;
    float var = csumsq[j] * inv - mean * mean;
    float sc = gamma[j] * rsqrtf(var + EPS);
    scale[j] = sc;
    shift[j] = beta[j] - mean * sc;
}

// ---------------- fused BN + MLP + skip-cat + out GEMM, bf16 MFMA, 32-row tiles
__global__ __launch_bounds__(256, 4) void mlp_kernel(
    const float* __restrict__ agg, const float* __restrict__ h,
    const float* __restrict__ scale, const float* __restrict__ shift,
    const unsigned short* __restrict__ w1b, const float* __restrict__ b1,
    const unsigned short* __restrict__ w2b, const float* __restrict__ b2,
    float* __restrict__ out, int N)
{
    __shared__ unsigned short xs[RTILE * XS_STRIDE];  // BN'd x, bf16
    __shared__ unsigned short cs[RTILE * CS_STRIDE];  // cat(h, x1), bf16; col255=0
    int tid = threadIdx.x;
    int row0 = blockIdx.x * RTILE;
    int lane = tid & 63;
    int wave = tid >> 6;

    // Phase A: BN(agg) -> xs ; h -> cs[:,0:127]
    {
        int j = tid & 127, rh = tid >> 7;
        float sc = scale[j], sf = shift[j];
        for (int i = 0; i < RTILE / 2; ++i) {
            int r = i * 2 + rh;
            long long grow = row0 + r;
            float x = 0.f, hv = 0.f;
            if (grow < N) {
                x = agg[grow * ADIM + j] * sc + sf;
                if (j < PDIM) hv = h[grow * PDIM + j];
            }
            xs[r * XS_STRIDE + j] = f2b(x);
            cs[r * CS_STRIDE + j] = f2b(hv);   // col 127 overwritten by x1[0] in B
        }
        if (tid < RTILE) cs[tid * CS_STRIDE + 255] = 0;  // zero pad col
    }
    __syncthreads();

    // Phase B: x1 = relu(x @ w1^T + b1) -> cs[:,127:255]
    // wave: col-tiles {2w, 2w+1} x row-tiles {0,1}
    {
        int arow = lane & 15, akg = lane >> 4;
        bf16x8 afr[2][4];
        #pragma unroll
        for (int rt = 0; rt < 2; ++rt)
            #pragma unroll
            for (int ks = 0; ks < 4; ++ks)
                afr[rt][ks] = *reinterpret_cast<const bf16x8*>(
                    &xs[(rt * 16 + arow) * XS_STRIDE + ks * 32 + akg * 8]);
        #pragma unroll
        for (int t = 0; t < 2; ++t) {
            int bcol = (wave * 2 + t) * 16 + (lane & 15);
            bf16x8 bfr[4];
            #pragma unroll
            for (int ks = 0; ks < 4; ++ks)
                bfr[ks] = *reinterpret_cast<const bf16x8*>(&w1b[bcol * ADIM + ks * 32 + akg * 8]);
            float bias = b1[bcol];
            #pragma unroll
            for (int rt = 0; rt < 2; ++rt) {
                f32x4 acc = {0.f, 0.f, 0.f, 0.f};
                #pragma unroll
                for (int ks = 0; ks < 4; ++ks)
                    acc = __builtin_amdgcn_mfma_f32_16x16x32_bf16(afr[rt][ks], bfr[ks], acc, 0, 0, 0);
                #pragma unroll
                for (int i = 0; i < 4; ++i) {
                    int r = rt * 16 + (lane >> 4) * 4 + i;
                    float x1 = fmaxf(acc[i] + bias, 0.f);
                    cs[r * CS_STRIDE + PDIM + bcol] = f2b(x1);
                }
            }
        }
    }
    __syncthreads();

    // Phase C: out = cat(h,x1) @ w2^T + b2
    // wave: o-tiles {4w..4w+3} x row-tiles {0,1}; A-frags persistent in regs
    {
        int arow = lane & 15, akg = lane >> 4;
        bf16x8 caf[2][8];
        #pragma unroll
        for (int rt = 0; rt < 2; ++rt)
            #pragma unroll
            for (int ks = 0; ks < 8; ++ks)
                caf[rt][ks] = *reinterpret_cast<const bf16x8*>(
                    &cs[(rt * 16 + arow) * CS_STRIDE + ks * 32 + akg * 8]);
        #pragma unroll
        for (int t = 0; t < 4; ++t) {
            int o = (wave * 4 + t) * 16 + (lane & 15);
            bf16x8 bfr[8];
            #pragma unroll
            for (int ks = 0; ks < 8; ++ks)
                bfr[ks] = *reinterpret_cast<const bf16x8*>(&w2b[o * 256 + ks * 32 + akg * 8]);
            float bias = (o < ODIM) ? b2[o] : 0.f;
            #pragma unroll
            for (int rt = 0; rt < 2; ++rt) {
                f32x4 acc = {0.f, 0.f, 0.f, 0.f};
                #pragma unroll
                for (int ks = 0; ks < 8; ++ks)
                    acc = __builtin_amdgcn_mfma_f32_16x16x32_bf16(caf[rt][ks], bfr[ks], acc, 0, 0, 0);
                if (o < ODIM) {
                    #pragma unroll
                    for (int i = 0; i < 4; ++i) {
                        long long grow = row0 + rt * 16 + (lane >> 4) * 4 + i;
                        if (grow < N) out[grow * ODIM + o] = acc[i] + bias;
                    }
                }
            }
        }
    }
}

extern "C" void kernel_launch(void* const* d_in, const int* in_sizes, int n_in,
                              void* d_out, int out_size, void* d_ws, size_t ws_size,
                              hipStream_t stream)
{
    const int*   u     = (const int*)d_in[0];
    const int*   v     = (const int*)d_in[1];
    const float* g     = (const float*)d_in[2];
    const float* h     = (const float*)d_in[3];
    const float* ru    = (const float*)d_in[4];
    const float* rv    = (const float*)d_in[5];
    const float* gamma = (const float*)d_in[6];
    const float* beta  = (const float*)d_in[7];
    const float* w1w   = (const float*)d_in[8];
    const float* w1b_f = (const float*)d_in[9];
    const float* w2w   = (const float*)d_in[10];
    const float* w2b_f = (const float*)d_in[11];

    int E = in_sizes[0];
    int N = in_sizes[3] / PDIM;

    // ws layout: [cnt N][csum 128][csumsq 128][scale 128][shift 128]
    //            [bucket N*CAP][agg N*128][w1b 128*128 u16][w2b 256*256 u16]
    int*   cnt    = (int*)d_ws;
    float* csum   = (float*)d_ws + N;
    float* csumsq = csum + ADIM;
    float* scale  = csumsq + ADIM;
    float* shift  = scale + ADIM;
    int*   bucket = (int*)(shift + ADIM);
    float* agg    = (float*)(bucket + (long long)N * CAP);
    unsigned short* w1b = (unsigned short*)(agg + (long long)N * ADIM);
    unsigned short* w2b = w1b + ADIM * ADIM;

    // zero cnt + csum + csumsq (adjacent; must be re-zeroed every call)
    (void)hipMemsetAsync(cnt, 0, ((size_t)N + 2 * ADIM) * sizeof(float), stream);

    int nbB = (E + 255) / 256;
    int nbW = (65536 + ADIM * ADIM + 255) / 256;
    build_kernel<<<nbB + nbW, 256, 0, stream>>>(u, v, cnt, bucket, E, nbB,
                                                w1w, w2w, w1b, w2b);

    int gblocks = (N + 7) / 8;   // 8 half-waves (nodes) per 256-thread block
    gather_kernel<<<gblocks, 256, 0, stream>>>(cnt, bucket, g, ru, rv,
                                               agg, csum, csumsq, N);

    finalize_kernel<<<1, 128, 0, stream>>>(csum, csumsq, gamma, beta, scale, shift, N);

    int mblocks = (N + RTILE - 1) / RTILE;
    mlp_kernel<<<mblocks, 256, 0, stream>>>(agg, h, scale, shift, w1b, w1b_f, w2b, w2b_f,
                                            (float*)d_out, N);
}

// Round 10
// 293.359 us; speedup vs baseline: 8.7275x; 8.7275x over previous
//
#include <hip/hip_runtime.h>

constexpr int PDIM = 127;   // previous_embed_size
constexpr int ADIM = 128;   // agg features
constexpr int ODIM = 255;   // w2 out size
constexpr int RTILE = 32;
constexpr int CAP = 80;     // bucket capacity per node (deg ~ Pois(20))
constexpr float EPS = 1e-5f;

constexpr int XS_STRIDE = 136;  // bf16 elems; 272B row stride (16B-aligned rows)
constexpr int CS_STRIDE = 264;  // 528B row stride

typedef short bf16x8 __attribute__((ext_vector_type(8)));
typedef float f32x4 __attribute__((ext_vector_type(4)));

__device__ inline unsigned short f2b(float x) {  // f32 -> bf16 RNE
    unsigned u = __builtin_bit_cast(unsigned, x);
    u += 0x7FFF + ((u >> 16) & 1);
    return (unsigned short)(u >> 16);
}

// ---------------- build: buckets + (tail blocks) weight conversion
// code = e | (side << 20); side 0 -> contribution is ru[e], side 1 -> rv[e]
__global__ __launch_bounds__(256) void build_kernel(
    const int* __restrict__ u, const int* __restrict__ v,
    int* __restrict__ cnt, int* __restrict__ bucket, int E, int nbB,
    const float* __restrict__ w1, const float* __restrict__ w2,
    unsigned short* __restrict__ w1b, unsigned short* __restrict__ w2b)
{
    int b = blockIdx.x;
    if (b < nbB) {
        int e = b * 256 + threadIdx.x;
        if (e >= E) return;
        int vn = v[e];
        int slot = atomicAdd(&cnt[vn], 1);
        if (slot < CAP) bucket[(long long)vn * CAP + slot] = e;            // side 0
        int un = u[e];
        slot = atomicAdd(&cnt[un], 1);
        if (slot < CAP) bucket[(long long)un * CAP + slot] = e | (1 << 20); // side 1
    } else {
        int t = (b - nbB) * 256 + threadIdx.x;
        if (t < 65536) {
            int o = t >> 8, k = t & 255;
            w2b[t] = (o < ODIM && k < ODIM) ? f2b(w2[o * ODIM + k]) : (unsigned short)0;
        } else {
            int s = t - 65536;   // 128*128 = 16384
            if (s < ADIM * ADIM) w1b[s] = f2b(w1[s]);
        }
    }
}

// ---------------- gather: one HALF-WAVE per node; lane l owns cols 4l..4l+3
// (lane 31: quad at 123 -> cols 124..126 via .y.z.w; col 127 = sum g[e],
//  accumulated by lane 31 only). No barrier, no stats — waves retire freely.
__global__ __launch_bounds__(256) void gather_kernel(
    const int* __restrict__ cnt, const int* __restrict__ bucket,
    const float* __restrict__ g,
    const float* __restrict__ ru, const float* __restrict__ rv,
    float* __restrict__ agg, int N)
{
    __shared__ int codes[8][CAP];   // 8 half-waves per 256-thread block
    int tid = threadIdx.x;
    int hw = tid >> 5;              // half-wave id in block
    int sub = tid & 31;             // lane within half-wave
    long long node = (long long)blockIdx.x * 8 + hw;
    bool valid = (node < N);
    int nd = valid ? (int)node : 0;
    int deg = valid ? cnt[nd] : 0;
    if (deg > CAP) deg = CAP;
    const int* bkt = bucket + (long long)nd * CAP;
    // stage codes (coalesced; same-wave DS ordering, no barrier needed)
    codes[hw][sub] = bkt[sub];
    codes[hw][32 + sub] = bkt[32 + sub];
    if (sub < CAP - 64) codes[hw][64 + sub] = bkt[64 + sub];

    int eoff = (sub < 31) ? 4 * sub : 123;   // element offset of this lane's quad
    f32x4 acc = {0.f, 0.f, 0.f, 0.f};
    float gacc = 0.f;
    bool g31 = (sub == 31);
    int d = 0;
    for (; d + 4 <= deg; d += 4) {
        f32x4 vb[4];
        float gb[4];
        #pragma unroll
        for (int k = 0; k < 4; ++k) {
            int c = codes[hw][d + k];
            int e = c & 0xFFFFF;
            const float* s = (c & (1 << 20)) ? rv : ru;
            vb[k] = *reinterpret_cast<const f32x4*>(s + (long long)e * PDIM + eoff);
            gb[k] = g31 ? g[e] : 0.f;
        }
        #pragma unroll
        for (int k = 0; k < 4; ++k) { acc += vb[k]; gacc += gb[k]; }
    }
    for (; d < deg; ++d) {
        int c = codes[hw][d];
        int e = c & 0xFFFFF;
        const float* s = (c & (1 << 20)) ? rv : ru;
        acc += *reinterpret_cast<const f32x4*>(s + (long long)e * PDIM + eoff);
        if (g31) gacc += g[e];
    }
    if (!valid) return;
    float* arow = agg + node * ADIM;
    if (sub < 31) {
        *reinterpret_cast<f32x4*>(arow + 4 * sub) = acc;
    } else {
        f32x4 o; o.x = acc.y; o.y = acc.z; o.z = acc.w; o.w = gacc;
        *reinterpret_cast<f32x4*>(arow + 124) = o;
    }
}

// ---------------- per-column sum / sumsq over rows (block-level pre-reduce
// in LDS, then one atomic per column per block -> low same-address fan-in)
__global__ __launch_bounds__(256) void colstats_kernel(
    const float* __restrict__ agg, float* __restrict__ csum,
    float* __restrict__ csumsq, int N)
{
    int j = threadIdx.x & 127;
    int rh = threadIdx.x >> 7;
    float s = 0.f, ss = 0.f;
    for (int r = blockIdx.x * 2 + rh; r < N; r += gridDim.x * 2) {
        float x = agg[(long long)r * ADIM + j];
        s += x; ss += x * x;
    }
    __shared__ float sh[2][128];
    __shared__ float sh2[2][128];
    sh[rh][j] = s; sh2[rh][j] = ss;
    __syncthreads();
    if (threadIdx.x < 128) {
        unsafeAtomicAdd(&csum[j], sh[0][j] + sh[1][j]);
        unsafeAtomicAdd(&csumsq[j], sh2[0][j] + sh2[1][j]);
    }
}

// ---------------- mean/var -> BN scale/shift
__global__ void finalize_kernel(const float* __restrict__ csum,
                                const float* __restrict__ csumsq,
                                const float* __restrict__ gamma,
                                const float* __restrict__ beta,
                                float* __restrict__ scale,
                                float* __restrict__ shift, int N)
{
    int j = threadIdx.x;
    if (j >= ADIM) return;
    float inv = 1.f / (float)N;
    float mean = csum[j] * inv;
    float var = csumsq[j] * inv - mean * mean;
    float sc = gamma[j] * rsqrtf(var + EPS);
    scale[j] = sc;
    shift[j] = beta[j] - mean * sc;
}

// ---------------- fused BN + MLP + skip-cat + out GEMM, bf16 MFMA, 32-row tiles
__global__ __launch_bounds__(256, 4) void mlp_kernel(
    const float* __restrict__ agg, const float* __restrict__ h,
    const float* __restrict__ scale, const float* __restrict__ shift,
    const unsigned short* __restrict__ w1b, const float* __restrict__ b1,
    const unsigned short* __restrict__ w2b, const float* __restrict__ b2,
    float* __restrict__ out, int N)
{
    __shared__ unsigned short xs[RTILE * XS_STRIDE];  // BN'd x, bf16
    __shared__ unsigned short cs[RTILE * CS_STRIDE];  // cat(h, x1), bf16; col255=0
    int tid = threadIdx.x;
    int row0 = blockIdx.x * RTILE;
    int lane = tid & 63;
    int wave = tid >> 6;

    // Phase A: BN(agg) -> xs ; h -> cs[:,0:127]
    {
        int j = tid & 127, rh = tid >> 7;
        float sc = scale[j], sf = shift[j];
        for (int i = 0; i < RTILE / 2; ++i) {
            int r = i * 2 + rh;
            long long grow = row0 + r;
            float x = 0.f, hv = 0.f;
            if (grow < N) {
                x = agg[grow * ADIM + j] * sc + sf;
                if (j < PDIM) hv = h[grow * PDIM + j];
            }
            xs[r * XS_STRIDE + j] = f2b(x);
            cs[r * CS_STRIDE + j] = f2b(hv);   // col 127 overwritten by x1[0] in B
        }
        if (tid < RTILE) cs[tid * CS_STRIDE + 255] = 0;  // zero pad col
    }
    __syncthreads();

    // Phase B: x1 = relu(x @ w1^T + b1) -> cs[:,127:255]
    // wave: col-tiles {2w, 2w+1} x row-tiles {0,1}
    {
        int arow = lane & 15, akg = lane >> 4;
        bf16x8 afr[2][4];
        #pragma unroll
        for (int rt = 0; rt < 2; ++rt)
            #pragma unroll
            for (int ks = 0; ks < 4; ++ks)
                afr[rt][ks] = *reinterpret_cast<const bf16x8*>(
                    &xs[(rt * 16 + arow) * XS_STRIDE + ks * 32 + akg * 8]);
        #pragma unroll
        for (int t = 0; t < 2; ++t) {
            int bcol = (wave * 2 + t) * 16 + (lane & 15);
            bf16x8 bfr[4];
            #pragma unroll
            for (int ks = 0; ks < 4; ++ks)
                bfr[ks] = *reinterpret_cast<const bf16x8*>(&w1b[bcol * ADIM + ks * 32 + akg * 8]);
            float bias = b1[bcol];
            #pragma unroll
            for (int rt = 0; rt < 2; ++rt) {
                f32x4 acc = {0.f, 0.f, 0.f, 0.f};
                #pragma unroll
                for (int ks = 0; ks < 4; ++ks)
                    acc = __builtin_amdgcn_mfma_f32_16x16x32_bf16(afr[rt][ks], bfr[ks], acc, 0, 0, 0);
                #pragma unroll
                for (int i = 0; i < 4; ++i) {
                    int r = rt * 16 + (lane >> 4) * 4 + i;
                    float x1 = fmaxf(acc[i] + bias, 0.f);
                    cs[r * CS_STRIDE + PDIM + bcol] = f2b(x1);
                }
            }
        }
    }
    __syncthreads();

    // Phase C: out = cat(h,x1) @ w2^T + b2
    // wave: o-tiles {4w..4w+3} x row-tiles {0,1}; A-frags persistent in regs
    {
        int arow = lane & 15, akg = lane >> 4;
        bf16x8 caf[2][8];
        #pragma unroll
        for (int rt = 0; rt < 2; ++rt)
            #pragma unroll
            for (int ks = 0; ks < 8; ++ks)
                caf[rt][ks] = *reinterpret_cast<const bf16x8*>(
                    &cs[(rt * 16 + arow) * CS_STRIDE + ks * 32 + akg * 8]);
        #pragma unroll
        for (int t = 0; t < 4; ++t) {
            int o = (wave * 4 + t) * 16 + (lane & 15);
            bf16x8 bfr[8];
            #pragma unroll
            for (int ks = 0; ks < 8; ++ks)
                bfr[ks] = *reinterpret_cast<const bf16x8*>(&w2b[o * 256 + ks * 32 + akg * 8]);
            float bias = (o < ODIM) ? b2[o] : 0.f;
            #pragma unroll
            for (int rt = 0; rt < 2; ++rt) {
                f32x4 acc = {0.f, 0.f, 0.f, 0.f};
                #pragma unroll
                for (int ks = 0; ks < 8; ++ks)
                    acc = __builtin_amdgcn_mfma_f32_16x16x32_bf16(caf[rt][ks], bfr[ks], acc, 0, 0, 0);
                if (o < ODIM) {
                    #pragma unroll
                    for (int i = 0; i < 4; ++i) {
                        long long grow = row0 + rt * 16 + (lane >> 4) * 4 + i;
                        if (grow < N) out[grow * ODIM + o] = acc[i] + bias;
                    }
                }
            }
        }
    }
}

extern "C" void kernel_launch(void* const* d_in, const int* in_sizes, int n_in,
                              void* d_out, int out_size, void* d_ws, size_t ws_size,
                              hipStream_t stream)
{
    const int*   u     = (const int*)d_in[0];
    const int*   v     = (const int*)d_in[1];
    const float* g     = (const float*)d_in[2];
    const float* h     = (const float*)d_in[3];
    const float* ru    = (const float*)d_in[4];
    const float* rv    = (const float*)d_in[5];
    const float* gamma = (const float*)d_in[6];
    const float* beta  = (const float*)d_in[7];
    const float* w1w   = (const float*)d_in[8];
    const float* w1b_f = (const float*)d_in[9];
    const float* w2w   = (const float*)d_in[10];
    const float* w2b_f = (const float*)d_in[11];

    int E = in_sizes[0];
    int N = in_sizes[3] / PDIM;

    // ws layout: [cnt N][csum 128][csumsq 128][scale 128][shift 128]
    //            [bucket N*CAP][agg N*128][w1b 128*128 u16][w2b 256*256 u16]
    int*   cnt    = (int*)d_ws;
    float* csum   = (float*)d_ws + N;
    float* csumsq = csum + ADIM;
    float* scale  = csumsq + ADIM;
    float* shift  = scale + ADIM;
    int*   bucket = (int*)(shift + ADIM);
    float* agg    = (float*)(bucket + (long long)N * CAP);
    unsigned short* w1b = (unsigned short*)(agg + (long long)N * ADIM);
    unsigned short* w2b = w1b + ADIM * ADIM;

    // zero cnt + csum + csumsq (adjacent; must be re-zeroed every call)
    (void)hipMemsetAsync(cnt, 0, ((size_t)N + 2 * ADIM) * sizeof(float), stream);

    int nbB = (E + 255) / 256;
    int nbW = (65536 + ADIM * ADIM + 255) / 256;
    build_kernel<<<nbB + nbW, 256, 0, stream>>>(u, v, cnt, bucket, E, nbB,
                                                w1w, w2w, w1b, w2b);

    int gblocks = (N + 7) / 8;   // 8 half-waves (nodes) per 256-thread block
    gather_kernel<<<gblocks, 256, 0, stream>>>(cnt, bucket, g, ru, rv, agg, N);

    colstats_kernel<<<512, 256, 0, stream>>>(agg, csum, csumsq, N);
    finalize_kernel<<<1, 128, 0, stream>>>(csum, csumsq, gamma, beta, scale, shift, N);

    int mblocks = (N + RTILE - 1) / RTILE;
    mlp_kernel<<<mblocks, 256, 0, stream>>>(agg, h, scale, shift, w1b, w1b_f, w2b, w2b_f,
                                            (float*)d_out, N);
}